// Round 3
// baseline (8129.133 us; speedup 1.0000x reference)
//
#include <hip/hip_runtime.h>
#include <cstdint>
#include <cstddef>

#define BATCH   512
#define HIDDEN  512
#define EMB     512
#define VOCAB   4096
#define NOBJ    3
#define FEATIN  2048
#define FEATSZ  512
#define MAXLEN  40
#define TSTEPS  38
#define SOS     1
#define EOS     2
#define GIH     1536   // 3*HIDDEN

#define BK 16
#define BM 64
#define KW 128    // K-range per wave in k_step (4 waves x 128 = 512)
#define RP 66     // padded row stride for partial buffers (bank-conflict-free)

// per-step grid: 512 logits tiles (8m x 64n) + 192 gates tiles (8m x 24n); 64x64 tile per block
#define NLOGITS_BLK 512
#define NGATES_BLK  192
#define NSTEP_BLK   (NLOGITS_BLK + NGATES_BLK)

static __device__ __forceinline__ unsigned long long pack_key(float v, int col) {
    uint32_t u = __float_as_uint(v);
    u = (u & 0x80000000u) ? ~u : (u | 0x80000000u);   // order-preserving map
    return ((unsigned long long)u << 32) | (uint32_t)(VOCAB - 1 - col);  // low col wins ties
}

// ---------------- zero d_out + keys
__global__ __launch_bounds__(256) void k_zero(float* __restrict__ out, int n,
                                              unsigned long long* __restrict__ keys) {
    int tid = threadIdx.x;
    size_t base = (size_t)blockIdx.x * 4096;
#pragma unroll
    for (int s = 0; s < 4; ++s) {
        size_t i4 = base + (size_t)s * 1024 + (size_t)tid * 4;
        if (i4 + 3 < (size_t)n) {
            *(float4*)&out[i4] = make_float4(0.f, 0.f, 0.f, 0.f);
        } else {
            for (size_t j = i4; j < (size_t)n; ++j) out[j] = 0.f;
        }
    }
    size_t gi = (size_t)blockIdx.x * 256 + tid;
    if (gi < (size_t)TSTEPS * BATCH) keys[gi] = 0ULL;
}

// ---------------- feature embed (one-time): fe[1536,512] = feats @ featW^T + featb
__global__ __launch_bounds__(256) void k_fe(const float* __restrict__ feats,
                                            const float* __restrict__ featW,
                                            const float* __restrict__ featb,
                                            float* __restrict__ fe) {
    __shared__ float As[BK][BM];
    __shared__ float Bs[BK][BM];
    const int tid = threadIdx.x;
    const int m0 = blockIdx.y * BM, n0 = blockIdx.x * BM;
    const int tx = tid & 15, ty = tid >> 4;
    const int lrow = tid >> 2, lk = (tid & 3) << 2;
    float acc[4][4] = {};
    for (int k0 = 0; k0 < FEATIN; k0 += BK) {
        float4 a = *(const float4*)&feats[(size_t)(m0 + lrow) * FEATIN + k0 + lk];
        float4 b = *(const float4*)&featW[(size_t)(n0 + lrow) * FEATIN + k0 + lk];
        __syncthreads();
        As[lk+0][lrow] = a.x; As[lk+1][lrow] = a.y; As[lk+2][lrow] = a.z; As[lk+3][lrow] = a.w;
        Bs[lk+0][lrow] = b.x; Bs[lk+1][lrow] = b.y; Bs[lk+2][lrow] = b.z; Bs[lk+3][lrow] = b.w;
        __syncthreads();
#pragma unroll
        for (int kk = 0; kk < BK; ++kk) {
            float4 av = *(const float4*)&As[kk][ty * 4];
            float4 bv = *(const float4*)&Bs[kk][tx * 4];
            float ar[4] = {av.x, av.y, av.z, av.w};
            float br[4] = {bv.x, bv.y, bv.z, bv.w};
#pragma unroll
            for (int i = 0; i < 4; ++i)
#pragma unroll
                for (int j = 0; j < 4; ++j) acc[i][j] += ar[i] * br[j];
        }
    }
#pragma unroll
    for (int i = 0; i < 4; ++i) {
        int r = m0 + ty * 4 + i;
#pragma unroll
        for (int j = 0; j < 4; ++j) {
            int c = n0 + tx * 4 + j;
            fe[(size_t)r * FEATSZ + c] = acc[i][j] + featb[c];
        }
    }
}

// ---------------- h0 (one-time): h0 = ft[512,1539] @ initW^T + initb
__global__ __launch_bounds__(256) void k_h0(const float* __restrict__ fe,
                                            const float* __restrict__ initW,
                                            const float* __restrict__ initb,
                                            const int* __restrict__ targets,
                                            float* __restrict__ h) {
    __shared__ float As[BK][BM];
    __shared__ float Bs[BK][BM];
    const int tid = threadIdx.x;
    const int m0 = blockIdx.y * BM, n0 = blockIdx.x * BM;
    const int tx = tid & 15, ty = tid >> 4;
    const int lrow = tid >> 2, lk = (tid & 3) << 2;
    float acc[4][4] = {};
    const int K = NOBJ * FEATSZ;  // 1536
    for (int k0 = 0; k0 < K; k0 += BK) {
        float4 a = *(const float4*)&fe[(size_t)(m0 + lrow) * K + k0 + lk];
        float breg[4];
#pragma unroll
        for (int i = 0; i < 4; ++i) {
            int ka = k0 + lk + i;
            breg[i] = initW[(size_t)(n0 + lrow) * 1539 + ka + (ka >> 9)];
        }
        __syncthreads();
        As[lk+0][lrow] = a.x; As[lk+1][lrow] = a.y; As[lk+2][lrow] = a.z; As[lk+3][lrow] = a.w;
#pragma unroll
        for (int i = 0; i < 4; ++i) Bs[lk + i][lrow] = breg[i];
        __syncthreads();
#pragma unroll
        for (int kk = 0; kk < BK; ++kk) {
            float4 av = *(const float4*)&As[kk][ty * 4];
            float4 bv = *(const float4*)&Bs[kk][tx * 4];
            float ar[4] = {av.x, av.y, av.z, av.w};
            float br[4] = {bv.x, bv.y, bv.z, bv.w};
#pragma unroll
            for (int i = 0; i < 4; ++i)
#pragma unroll
                for (int j = 0; j < 4; ++j) acc[i][j] += ar[i] * br[j];
        }
    }
#pragma unroll
    for (int i = 0; i < 4; ++i) {
        int r = m0 + ty * 4 + i;
        int tg = targets[r];
#pragma unroll
        for (int j = 0; j < 4; ++j) {
            int c = n0 + tx * 4 + j;
            h[(size_t)r * HIDDEN + c] =
                acc[i][j] + initb[c] + initW[(size_t)c * 1539 + tg * 513 + 512];
        }
    }
}

// ---------------- P[4096,1536] = embW @ Wih^T + bih (one-time; bih folded)
__global__ __launch_bounds__(256) void k_P(const float* __restrict__ embW,
                                           const float* __restrict__ Wih,
                                           const float* __restrict__ bih,
                                           float* __restrict__ P) {
    __shared__ __align__(16) float As[2][BK][BM + 4];
    __shared__ __align__(16) float Bs[2][BK][128 + 4];
    const int tid = threadIdx.x;
    const int arow = tid >> 2, ak = (tid & 3) << 2;
    const int tx = tid & 15, ty = tid >> 4;
    const int m0 = blockIdx.y * BM, n0 = blockIdx.x * 128;
    const float* Ap = embW + (size_t)(m0 + arow) * EMB;
    const float* Bp0 = Wih + (size_t)(n0 + arow) * EMB;
    const float* Bp1 = Wih + (size_t)(n0 + 64 + arow) * EMB;
    float4 aR = *(const float4*)&Ap[ak];
    float4 bR0 = *(const float4*)&Bp0[ak];
    float4 bR1 = *(const float4*)&Bp1[ak];
    float acc[4][8] = {};
    int buf = 0;
    for (int k0 = 0; k0 < EMB; k0 += BK) {
        As[buf][ak+0][arow] = aR.x; As[buf][ak+1][arow] = aR.y;
        As[buf][ak+2][arow] = aR.z; As[buf][ak+3][arow] = aR.w;
        Bs[buf][ak+0][arow] = bR0.x; Bs[buf][ak+1][arow] = bR0.y;
        Bs[buf][ak+2][arow] = bR0.z; Bs[buf][ak+3][arow] = bR0.w;
        Bs[buf][ak+0][arow+64] = bR1.x; Bs[buf][ak+1][arow+64] = bR1.y;
        Bs[buf][ak+2][arow+64] = bR1.z; Bs[buf][ak+3][arow+64] = bR1.w;
        __syncthreads();
        if (k0 + BK < EMB) {
            aR  = *(const float4*)&Ap[k0 + BK + ak];
            bR0 = *(const float4*)&Bp0[k0 + BK + ak];
            bR1 = *(const float4*)&Bp1[k0 + BK + ak];
        }
#pragma unroll
        for (int kk = 0; kk < BK; ++kk) {
            float4 av  = *(const float4*)&As[buf][kk][ty * 4];
            float4 bv0 = *(const float4*)&Bs[buf][kk][tx * 4];
            float4 bv1 = *(const float4*)&Bs[buf][kk][64 + tx * 4];
            float ar[4] = {av.x, av.y, av.z, av.w};
            float br[8] = {bv0.x, bv0.y, bv0.z, bv0.w, bv1.x, bv1.y, bv1.z, bv1.w};
#pragma unroll
            for (int i = 0; i < 4; ++i)
#pragma unroll
                for (int j = 0; j < 8; ++j) acc[i][j] += ar[i] * br[j];
        }
        buf ^= 1;
    }
    float4 bi0 = *(const float4*)&bih[n0 + tx * 4];
    float4 bi1 = *(const float4*)&bih[n0 + 64 + tx * 4];
#pragma unroll
    for (int i = 0; i < 4; ++i) {
        int r = m0 + ty * 4 + i;
        *(float4*)&P[(size_t)r * GIH + n0 + tx * 4] =
            make_float4(acc[i][0] + bi0.x, acc[i][1] + bi0.y, acc[i][2] + bi0.z, acc[i][3] + bi0.w);
        *(float4*)&P[(size_t)r * GIH + n0 + 64 + tx * 4] =
            make_float4(acc[i][4] + bi1.x, acc[i][5] + bi1.y, acc[i][6] + bi1.z, acc[i][7] + bi1.w);
    }
}

// ---------------- per-step GEMM: 256 threads = 4 waves SPLIT-K over one 64x64 tile.
// Each wave: K-range [wave*128, wave*128+128), 8x8 acc/lane, wave-private LDS staging
// (no barriers in main loop). Then 3-barrier LDS reduction of the 4 partials.
// blocks [0,512): logits tiles (B = outW, epilogue = argmax keys)
// blocks [512,704): gatesH tiles (B = Whh, epilogue = write Gp)
__global__ __launch_bounds__(256, 4) void k_step(const float* __restrict__ h,
                                                 const float* __restrict__ Whh,
                                                 float* __restrict__ Gp,
                                                 const float* __restrict__ outW,
                                                 const float* __restrict__ outb,
                                                 const float* __restrict__ gum_t,
                                                 unsigned long long* __restrict__ keys_t,
                                                 int bx_off) {
    // 8448 floats = 33KB: main loop uses [wave*2048 .. +2048) as As(1024)+Bs(1024);
    // reduction overlays R0 = [0, 64*RP), R1 = [64*RP, 128*RP).
    __shared__ float smem[2 * BM * RP];
    const int tid = threadIdx.x;
    const int wave = tid >> 6, lane = tid & 63;
    const int bx = (int)blockIdx.x + bx_off;
    const int is_logits = (bx < NLOGITS_BLK);
    int m0, n0;
    const float* Bbase;
    if (is_logits) {
        m0 = (bx >> 6) * 64; n0 = (bx & 63) * 64; Bbase = outW;
    } else {
        const int gx = bx - NLOGITS_BLK;        // 0..191
        m0 = (gx / 24) * 64; n0 = (gx % 24) * 64; Bbase = Whh;
    }
    const float* Ap = h + (size_t)(m0 + lane) * HIDDEN + wave * KW;
    const float* Bp = Bbase + (size_t)(n0 + lane) * HIDDEN + wave * KW;
    float* As = smem + wave * 2048;        // [16][64] wave-private
    float* Bs = As + 1024;                 // [16][64]
    const int ty = lane >> 3, tx = lane & 7;

    float4 aR[4], bR[4];
#pragma unroll
    for (int q = 0; q < 4; ++q) {
        aR[q] = *(const float4*)&Ap[q * 4];
        bR[q] = *(const float4*)&Bp[q * 4];
    }
    float acc[8][8] = {};
#pragma unroll 1
    for (int k0 = 0; k0 < KW; k0 += BK) {
        // wave-private staging: lane t owns column t; intra-wave LDS ordering is in-order
#pragma unroll
        for (int q = 0; q < 4; ++q) {
            As[(q*4+0)*64 + lane] = aR[q].x; As[(q*4+1)*64 + lane] = aR[q].y;
            As[(q*4+2)*64 + lane] = aR[q].z; As[(q*4+3)*64 + lane] = aR[q].w;
            Bs[(q*4+0)*64 + lane] = bR[q].x; Bs[(q*4+1)*64 + lane] = bR[q].y;
            Bs[(q*4+2)*64 + lane] = bR[q].z; Bs[(q*4+3)*64 + lane] = bR[q].w;
        }
        if (k0 + BK < KW) {
#pragma unroll
            for (int q = 0; q < 4; ++q) {
                aR[q] = *(const float4*)&Ap[k0 + BK + q * 4];
                bR[q] = *(const float4*)&Bp[k0 + BK + q * 4];
            }
        }
#pragma unroll
        for (int kk = 0; kk < BK; ++kk) {
            float4 a0 = *(const float4*)&As[kk * 64 + ty * 8];
            float4 a1 = *(const float4*)&As[kk * 64 + ty * 8 + 4];
            float4 b0 = *(const float4*)&Bs[kk * 64 + tx * 8];
            float4 b1 = *(const float4*)&Bs[kk * 64 + tx * 8 + 4];
            float ar[8] = {a0.x, a0.y, a0.z, a0.w, a1.x, a1.y, a1.z, a1.w};
            float br[8] = {b0.x, b0.y, b0.z, b0.w, b1.x, b1.y, b1.z, b1.w};
#pragma unroll
            for (int i = 0; i < 8; ++i)
#pragma unroll
                for (int j = 0; j < 8; ++j) acc[i][j] += ar[i] * br[j];
        }
    }

    // ---- reduce 4 wave-partials: R0 = w0 + w2, R1 = w1 + w3, result = R0 + R1
    float* R0 = smem;
    float* R1 = smem + BM * RP;
    __syncthreads();
    if (wave < 2) {
        float* R = (wave == 0) ? R0 : R1;
#pragma unroll
        for (int i = 0; i < 8; ++i) {
            int r = ty * 8 + i;
            *(float4*)&R[r * RP + tx * 8] =
                make_float4(acc[i][0], acc[i][1], acc[i][2], acc[i][3]);
            *(float4*)&R[r * RP + tx * 8 + 4] =
                make_float4(acc[i][4], acc[i][5], acc[i][6], acc[i][7]);
        }
    }
    __syncthreads();
    if (wave >= 2) {
        float* R = (wave == 2) ? R0 : R1;
#pragma unroll
        for (int i = 0; i < 8; ++i) {
            int r = ty * 8 + i;
            float4 p0 = *(const float4*)&R[r * RP + tx * 8];
            float4 p1 = *(const float4*)&R[r * RP + tx * 8 + 4];
            p0.x += acc[i][0]; p0.y += acc[i][1]; p0.z += acc[i][2]; p0.w += acc[i][3];
            p1.x += acc[i][4]; p1.y += acc[i][5]; p1.z += acc[i][6]; p1.w += acc[i][7];
            *(float4*)&R[r * RP + tx * 8]     = p0;
            *(float4*)&R[r * RP + tx * 8 + 4] = p1;
        }
    }
    __syncthreads();

    // ---- epilogue: wave w owns rows [w*16, w*16+16); 4 lanes per row, 16 cols per lane
    const int row = wave * 16 + (lane >> 2);
    const int c0 = (lane & 3) * 16;
    float v[16];
#pragma unroll
    for (int g = 0; g < 4; ++g) {
        float4 s0 = *(const float4*)&R0[row * RP + c0 + g * 4];
        float4 s1 = *(const float4*)&R1[row * RP + c0 + g * 4];
        v[g*4+0] = s0.x + s1.x; v[g*4+1] = s0.y + s1.y;
        v[g*4+2] = s0.z + s1.z; v[g*4+3] = s0.w + s1.w;
    }
    if (is_logits) {
        const int r = m0 + row;
        unsigned long long best = 0ULL;
#pragma unroll
        for (int g = 0; g < 4; ++g) {
            float4 gg = *(const float4*)&gum_t[(size_t)r * VOCAB + n0 + c0 + g * 4];
            float4 ob = *(const float4*)&outb[n0 + c0 + g * 4];
            float gv[4] = {gg.x, gg.y, gg.z, gg.w};
            float obv[4] = {ob.x, ob.y, ob.z, ob.w};
#pragma unroll
            for (int e = 0; e < 4; ++e) {
                unsigned long long key =
                    pack_key(v[g*4+e] + obv[e] + gv[e], n0 + c0 + g * 4 + e);
                if (key > best) best = key;
            }
        }
#pragma unroll
        for (int s = 1; s < 4; s <<= 1) {
            unsigned long long o = __shfl_xor(best, s);
            if (o > best) best = o;
        }
        if ((lane & 3) == 0) atomicMax(&keys_t[r], best);
    } else {
        float* Go = Gp + (size_t)(m0 + row) * GIH + n0 + c0;
#pragma unroll
        for (int g = 0; g < 4; ++g)
            *(float4*)&Go[g * 4] = make_float4(v[g*4+0], v[g*4+1], v[g*4+2], v[g*4+3]);
    }
}

// ---------------- GRU elementwise: h = (1-z)*n + z*h  (single full-K Gp; bih folded in P)
__global__ __launch_bounds__(256) void k_gru(const float* __restrict__ Gp,
                                             const float* __restrict__ P,
                                             const float* __restrict__ bhh,
                                             const unsigned long long* __restrict__ keys_prev,
                                             float* __restrict__ h) {
    int idx = blockIdx.x * 256 + threadIdx.x;    // 0..65535
    int b = idx >> 7;
    int j4 = (idx & 127) << 2;
    int tok = SOS;
    if (keys_prev) tok = (VOCAB - 1) - (int)(uint32_t)(keys_prev[b] & 0xffffffffULL);
    const float* Pr = P + (size_t)tok * GIH;
    const float* G0 = Gp + (size_t)b * GIH;
    float4 ir = *(const float4*)&Pr[j4];
    float4 iz = *(const float4*)&Pr[j4 + HIDDEN];
    float4 in_ = *(const float4*)&Pr[j4 + 2 * HIDDEN];
    float4 hr0 = *(const float4*)&G0[j4];
    float4 hz0 = *(const float4*)&G0[j4 + HIDDEN];
    float4 hn0 = *(const float4*)&G0[j4 + 2 * HIDDEN];
    float4 bhr = *(const float4*)&bhh[j4];
    float4 bhz = *(const float4*)&bhh[j4 + HIDDEN];
    float4 bhn = *(const float4*)&bhh[j4 + 2 * HIDDEN];
    float4 ho = *(const float4*)&h[(size_t)b * HIDDEN + j4];
    float irr[4] = {ir.x, ir.y, ir.z, ir.w};
    float izz[4] = {iz.x, iz.y, iz.z, iz.w};
    float inn[4] = {in_.x, in_.y, in_.z, in_.w};
    float hrr[4] = {hr0.x + bhr.x, hr0.y + bhr.y, hr0.z + bhr.z, hr0.w + bhr.w};
    float hzz[4] = {hz0.x + bhz.x, hz0.y + bhz.y, hz0.z + bhz.z, hz0.w + bhz.w};
    float hnn[4] = {hn0.x + bhn.x, hn0.y + bhn.y, hn0.z + bhn.z, hn0.w + bhn.w};
    float hov[4] = {ho.x, ho.y, ho.z, ho.w};
    float res[4];
#pragma unroll
    for (int i = 0; i < 4; ++i) {
        float r = 1.0f / (1.0f + expf(-(irr[i] + hrr[i])));
        float z = 1.0f / (1.0f + expf(-(izz[i] + hzz[i])));
        float n = tanhf(inn[i] + r * hnn[i]);
        res[i] = (1.0f - z) * n + z * hov[i];
    }
    *(float4*)&h[(size_t)b * HIDDEN + j4] = make_float4(res[0], res[1], res[2], res[3]);
}

// ---------------- finalize
__global__ __launch_bounds__(256) void k_final(const unsigned long long* __restrict__ keys,
                                               float* __restrict__ out) {
    int b = blockIdx.x * 256 + threadIdx.x;
    if (b >= BATCH) return;
    int toks[TSTEPS];
    int len = 1;
    bool done = false;
#pragma unroll
    for (int t = 0; t < TSTEPS; ++t) {
        int tok = (VOCAB - 1) - (int)(uint32_t)(keys[(size_t)t * BATCH + b] & 0xffffffffULL);
        toks[t] = tok;
        if (!done) len++;
        if (tok == EOS) done = true;
    }
    if (!done) len++;
    float* lang = out + (size_t)b * MAXLEN * VOCAB;
    lang[SOS] = 1.0f;
#pragma unroll
    for (int t = 0; t < TSTEPS; ++t) {
        int pos = t + 1;
        if (pos < len) lang[(size_t)pos * VOCAB + toks[t]] = 1.0f;
    }
    if (len == MAXLEN) lang[(size_t)(MAXLEN - 1) * VOCAB + EOS] = 1.0f;
    out[(size_t)BATCH * MAXLEN * VOCAB + b] = (float)len;
    if (b == 0) out[(size_t)BATCH * MAXLEN * VOCAB + BATCH] = 0.0f;
}

extern "C" void kernel_launch(void* const* d_in, const int* in_sizes, int n_in,
                              void* d_out, int out_size, void* d_ws, size_t ws_size,
                              hipStream_t stream) {
    const float* feats = (const float*)d_in[0];
    const int*   targets = (const int*)d_in[1];
    const float* featW = (const float*)d_in[2];
    const float* featb = (const float*)d_in[3];
    const float* embW  = (const float*)d_in[4];
    const float* initW = (const float*)d_in[5];
    const float* initb = (const float*)d_in[6];
    const float* Wih   = (const float*)d_in[7];
    const float* Whh   = (const float*)d_in[8];
    const float* bih   = (const float*)d_in[9];
    const float* bhh   = (const float*)d_in[10];
    const float* outW  = (const float*)d_in[11];
    const float* outb  = (const float*)d_in[12];
    const float* gumbel = (const float*)d_in[13];
    float* out = (float*)d_out;

    // workspace layout:
    char* ws = (char*)d_ws;
    float* h  = (float*)(ws);                                    // 1 MB
    unsigned long long* keys = (unsigned long long*)(ws + (1 << 20));  // 152 KB
    float* Gp = (float*)(ws + 5 * (1 << 18));                    // @1.25 MB: 512x1536x4 = 3 MB
    float* fe = Gp;                                              // alias: fe (3 MB) dead before Gp use
    float* P  = (float*)(ws + 8 * (1 << 20));                    // @8 MB: 25.17 MB

    int zb = (out_size + 4095) / 4096;
    k_zero<<<dim3(zb), 256, 0, stream>>>(out, out_size, keys);

    k_fe<<<dim3(FEATSZ / BM, (BATCH * NOBJ) / BM), 256, 0, stream>>>(feats, featW, featb, fe);
    k_h0<<<dim3(HIDDEN / BM, BATCH / BM), 256, 0, stream>>>(fe, initW, initb, targets, h);
    k_P<<<dim3(GIH / 128, VOCAB / BM), 256, 0, stream>>>(embW, Wih, bih, P);

    // prime gatesH(0) from h0 — gates blocks only (bx_off=512)
    k_step<<<dim3(NGATES_BLK), 256, 0, stream>>>(h, Whh, Gp, outW, outb, gumbel, keys,
                                                 NLOGITS_BLK);

    for (int t = 0; t < TSTEPS; ++t) {
        const unsigned long long* kprev = (t == 0) ? nullptr : (keys + (size_t)(t - 1) * BATCH);
        k_gru<<<dim3(BATCH * HIDDEN / 4 / 256), 256, 0, stream>>>(Gp, P, bhh, kprev, h);
        int nblk = (t < TSTEPS - 1) ? NSTEP_BLK : NLOGITS_BLK;   // last step: logits only
        k_step<<<dim3(nblk), 256, 0, stream>>>(
            h, Whh, Gp, outW, outb, gumbel + (size_t)t * BATCH * VOCAB,
            keys + (size_t)t * BATCH, 0);
    }
    k_final<<<dim3(2), 256, 0, stream>>>(keys, out);
}

// Round 4
// 2806.330 us; speedup vs baseline: 2.8967x; 2.8967x over previous
//
#include <hip/hip_runtime.h>
#include <cstdint>
#include <cstddef>

#define BATCH   512
#define HIDDEN  512
#define EMB     512
#define VOCAB   4096
#define NOBJ    3
#define FEATIN  2048
#define FEATSZ  512
#define MAXLEN  40
#define TSTEPS  38
#define SOS     1
#define EOS     2
#define GIH     1536   // 3*HIDDEN

#define BK 16
#define BM 64
#define KW 128    // K-range per wave in k_step (4 waves x 128 = 512)
#define RP 66     // padded row stride for partial buffers (bank-conflict-free)

// per-step grid: 512 logits tiles (8m x 64n) + 192 gates tiles (8m x 24n); 64x64 tile per block
#define NLOGITS_BLK 512
#define NGATES_BLK  192
#define NSTEP_BLK   (NLOGITS_BLK + NGATES_BLK)

static __device__ __forceinline__ unsigned long long pack_key(float v, int col) {
    uint32_t u = __float_as_uint(v);
    u = (u & 0x80000000u) ? ~u : (u | 0x80000000u);   // order-preserving map
    return ((unsigned long long)u << 32) | (uint32_t)(VOCAB - 1 - col);  // low col wins ties
}

// ---------------- zero d_out + keys
__global__ __launch_bounds__(256) void k_zero(float* __restrict__ out, int n,
                                              unsigned long long* __restrict__ keys) {
    int tid = threadIdx.x;
    size_t base = (size_t)blockIdx.x * 4096;
#pragma unroll
    for (int s = 0; s < 4; ++s) {
        size_t i4 = base + (size_t)s * 1024 + (size_t)tid * 4;
        if (i4 + 3 < (size_t)n) {
            *(float4*)&out[i4] = make_float4(0.f, 0.f, 0.f, 0.f);
        } else {
            for (size_t j = i4; j < (size_t)n; ++j) out[j] = 0.f;
        }
    }
    size_t gi = (size_t)blockIdx.x * 256 + tid;
    if (gi < (size_t)TSTEPS * BATCH) keys[gi] = 0ULL;
}

// ---------------- feature embed (one-time): fe[1536,512] = feats @ featW^T + featb
__global__ __launch_bounds__(256) void k_fe(const float* __restrict__ feats,
                                            const float* __restrict__ featW,
                                            const float* __restrict__ featb,
                                            float* __restrict__ fe) {
    __shared__ float As[BK][BM];
    __shared__ float Bs[BK][BM];
    const int tid = threadIdx.x;
    const int m0 = blockIdx.y * BM, n0 = blockIdx.x * BM;
    const int tx = tid & 15, ty = tid >> 4;
    const int lrow = tid >> 2, lk = (tid & 3) << 2;
    float acc[4][4] = {};
    for (int k0 = 0; k0 < FEATIN; k0 += BK) {
        float4 a = *(const float4*)&feats[(size_t)(m0 + lrow) * FEATIN + k0 + lk];
        float4 b = *(const float4*)&featW[(size_t)(n0 + lrow) * FEATIN + k0 + lk];
        __syncthreads();
        As[lk+0][lrow] = a.x; As[lk+1][lrow] = a.y; As[lk+2][lrow] = a.z; As[lk+3][lrow] = a.w;
        Bs[lk+0][lrow] = b.x; Bs[lk+1][lrow] = b.y; Bs[lk+2][lrow] = b.z; Bs[lk+3][lrow] = b.w;
        __syncthreads();
#pragma unroll
        for (int kk = 0; kk < BK; ++kk) {
            float4 av = *(const float4*)&As[kk][ty * 4];
            float4 bv = *(const float4*)&Bs[kk][tx * 4];
            float ar[4] = {av.x, av.y, av.z, av.w};
            float br[4] = {bv.x, bv.y, bv.z, bv.w};
#pragma unroll
            for (int i = 0; i < 4; ++i)
#pragma unroll
                for (int j = 0; j < 4; ++j) acc[i][j] += ar[i] * br[j];
        }
    }
#pragma unroll
    for (int i = 0; i < 4; ++i) {
        int r = m0 + ty * 4 + i;
#pragma unroll
        for (int j = 0; j < 4; ++j) {
            int c = n0 + tx * 4 + j;
            fe[(size_t)r * FEATSZ + c] = acc[i][j] + featb[c];
        }
    }
}

// ---------------- h0 (one-time): h0 = ft[512,1539] @ initW^T + initb
__global__ __launch_bounds__(256) void k_h0(const float* __restrict__ fe,
                                            const float* __restrict__ initW,
                                            const float* __restrict__ initb,
                                            const int* __restrict__ targets,
                                            float* __restrict__ h) {
    __shared__ float As[BK][BM];
    __shared__ float Bs[BK][BM];
    const int tid = threadIdx.x;
    const int m0 = blockIdx.y * BM, n0 = blockIdx.x * BM;
    const int tx = tid & 15, ty = tid >> 4;
    const int lrow = tid >> 2, lk = (tid & 3) << 2;
    float acc[4][4] = {};
    const int K = NOBJ * FEATSZ;  // 1536
    for (int k0 = 0; k0 < K; k0 += BK) {
        float4 a = *(const float4*)&fe[(size_t)(m0 + lrow) * K + k0 + lk];
        float breg[4];
#pragma unroll
        for (int i = 0; i < 4; ++i) {
            int ka = k0 + lk + i;
            breg[i] = initW[(size_t)(n0 + lrow) * 1539 + ka + (ka >> 9)];
        }
        __syncthreads();
        As[lk+0][lrow] = a.x; As[lk+1][lrow] = a.y; As[lk+2][lrow] = a.z; As[lk+3][lrow] = a.w;
#pragma unroll
        for (int i = 0; i < 4; ++i) Bs[lk + i][lrow] = breg[i];
        __syncthreads();
#pragma unroll
        for (int kk = 0; kk < BK; ++kk) {
            float4 av = *(const float4*)&As[kk][ty * 4];
            float4 bv = *(const float4*)&Bs[kk][tx * 4];
            float ar[4] = {av.x, av.y, av.z, av.w};
            float br[4] = {bv.x, bv.y, bv.z, bv.w};
#pragma unroll
            for (int i = 0; i < 4; ++i)
#pragma unroll
                for (int j = 0; j < 4; ++j) acc[i][j] += ar[i] * br[j];
        }
    }
#pragma unroll
    for (int i = 0; i < 4; ++i) {
        int r = m0 + ty * 4 + i;
        int tg = targets[r];
#pragma unroll
        for (int j = 0; j < 4; ++j) {
            int c = n0 + tx * 4 + j;
            h[(size_t)r * HIDDEN + c] =
                acc[i][j] + initb[c] + initW[(size_t)c * 1539 + tg * 513 + 512];
        }
    }
}

// ---------------- P[4096,1536] = embW @ Wih^T + bih (one-time; bih folded)
__global__ __launch_bounds__(256) void k_P(const float* __restrict__ embW,
                                           const float* __restrict__ Wih,
                                           const float* __restrict__ bih,
                                           float* __restrict__ P) {
    __shared__ __align__(16) float As[2][BK][BM + 4];
    __shared__ __align__(16) float Bs[2][BK][128 + 4];
    const int tid = threadIdx.x;
    const int arow = tid >> 2, ak = (tid & 3) << 2;
    const int tx = tid & 15, ty = tid >> 4;
    const int m0 = blockIdx.y * BM, n0 = blockIdx.x * 128;
    const float* Ap = embW + (size_t)(m0 + arow) * EMB;
    const float* Bp0 = Wih + (size_t)(n0 + arow) * EMB;
    const float* Bp1 = Wih + (size_t)(n0 + 64 + arow) * EMB;
    float4 aR = *(const float4*)&Ap[ak];
    float4 bR0 = *(const float4*)&Bp0[ak];
    float4 bR1 = *(const float4*)&Bp1[ak];
    float acc[4][8] = {};
    int buf = 0;
    for (int k0 = 0; k0 < EMB; k0 += BK) {
        As[buf][ak+0][arow] = aR.x; As[buf][ak+1][arow] = aR.y;
        As[buf][ak+2][arow] = aR.z; As[buf][ak+3][arow] = aR.w;
        Bs[buf][ak+0][arow] = bR0.x; Bs[buf][ak+1][arow] = bR0.y;
        Bs[buf][ak+2][arow] = bR0.z; Bs[buf][ak+3][arow] = bR0.w;
        Bs[buf][ak+0][arow+64] = bR1.x; Bs[buf][ak+1][arow+64] = bR1.y;
        Bs[buf][ak+2][arow+64] = bR1.z; Bs[buf][ak+3][arow+64] = bR1.w;
        __syncthreads();
        if (k0 + BK < EMB) {
            aR  = *(const float4*)&Ap[k0 + BK + ak];
            bR0 = *(const float4*)&Bp0[k0 + BK + ak];
            bR1 = *(const float4*)&Bp1[k0 + BK + ak];
        }
#pragma unroll
        for (int kk = 0; kk < BK; ++kk) {
            float4 av  = *(const float4*)&As[buf][kk][ty * 4];
            float4 bv0 = *(const float4*)&Bs[buf][kk][tx * 4];
            float4 bv1 = *(const float4*)&Bs[buf][kk][64 + tx * 4];
            float ar[4] = {av.x, av.y, av.z, av.w};
            float br[8] = {bv0.x, bv0.y, bv0.z, bv0.w, bv1.x, bv1.y, bv1.z, bv1.w};
#pragma unroll
            for (int i = 0; i < 4; ++i)
#pragma unroll
                for (int j = 0; j < 8; ++j) acc[i][j] += ar[i] * br[j];
        }
        buf ^= 1;
    }
    float4 bi0 = *(const float4*)&bih[n0 + tx * 4];
    float4 bi1 = *(const float4*)&bih[n0 + 64 + tx * 4];
#pragma unroll
    for (int i = 0; i < 4; ++i) {
        int r = m0 + ty * 4 + i;
        *(float4*)&P[(size_t)r * GIH + n0 + tx * 4] =
            make_float4(acc[i][0] + bi0.x, acc[i][1] + bi0.y, acc[i][2] + bi0.z, acc[i][3] + bi0.w);
        *(float4*)&P[(size_t)r * GIH + n0 + 64 + tx * 4] =
            make_float4(acc[i][4] + bi1.x, acc[i][5] + bi1.y, acc[i][6] + bi1.z, acc[i][7] + bi1.w);
    }
}

// ---------------- per-step GEMM: 256 threads = 4 waves SPLIT-K over one 64x64 tile.
// Each wave: K-range [wave*128, wave*128+128), 8x8 acc/lane, wave-private LDS staging
// (no barriers in main loop). Then 3-barrier LDS reduction of the 4 partials.
// __launch_bounds__(256, 1): do NOT cap VGPRs for occupancy — the (256,4) variant was
// capped to 64 VGPRs and spilled the 8x8 accumulators to scratch (254MB fetch + 524MB
// write per dispatch, VALUBusy 10%). ~116 VGPRs still yields 4 waves/SIMD naturally.
__global__ __launch_bounds__(256, 1) void k_step(const float* __restrict__ h,
                                                 const float* __restrict__ Whh,
                                                 float* __restrict__ Gp,
                                                 const float* __restrict__ outW,
                                                 const float* __restrict__ outb,
                                                 const float* __restrict__ gum_t,
                                                 unsigned long long* __restrict__ keys_t,
                                                 int bx_off) {
    // 8448 floats = 33KB: main loop uses [wave*2048 .. +2048) as As(1024)+Bs(1024);
    // reduction overlays R0 = [0, 64*RP), R1 = [64*RP, 128*RP).
    __shared__ float smem[2 * BM * RP];
    const int tid = threadIdx.x;
    const int wave = tid >> 6, lane = tid & 63;
    const int bx = (int)blockIdx.x + bx_off;
    const int is_logits = (bx < NLOGITS_BLK);
    int m0, n0;
    const float* Bbase;
    if (is_logits) {
        m0 = (bx >> 6) * 64; n0 = (bx & 63) * 64; Bbase = outW;
    } else {
        const int gx = bx - NLOGITS_BLK;        // 0..191
        m0 = (gx / 24) * 64; n0 = (gx % 24) * 64; Bbase = Whh;
    }
    const float* Ap = h + (size_t)(m0 + lane) * HIDDEN + wave * KW;
    const float* Bp = Bbase + (size_t)(n0 + lane) * HIDDEN + wave * KW;
    float* As = smem + wave * 2048;        // [16][64] wave-private
    float* Bs = As + 1024;                 // [16][64]
    const int ty = lane >> 3, tx = lane & 7;

    float4 aR[4], bR[4];
#pragma unroll
    for (int q = 0; q < 4; ++q) {
        aR[q] = *(const float4*)&Ap[q * 4];
        bR[q] = *(const float4*)&Bp[q * 4];
    }
    float acc[8][8] = {};
#pragma unroll 1
    for (int k0 = 0; k0 < KW; k0 += BK) {
        // wave-private staging: lane t owns column t; intra-wave LDS ordering is in-order
#pragma unroll
        for (int q = 0; q < 4; ++q) {
            As[(q*4+0)*64 + lane] = aR[q].x; As[(q*4+1)*64 + lane] = aR[q].y;
            As[(q*4+2)*64 + lane] = aR[q].z; As[(q*4+3)*64 + lane] = aR[q].w;
            Bs[(q*4+0)*64 + lane] = bR[q].x; Bs[(q*4+1)*64 + lane] = bR[q].y;
            Bs[(q*4+2)*64 + lane] = bR[q].z; Bs[(q*4+3)*64 + lane] = bR[q].w;
        }
        if (k0 + BK < KW) {
#pragma unroll
            for (int q = 0; q < 4; ++q) {
                aR[q] = *(const float4*)&Ap[k0 + BK + q * 4];
                bR[q] = *(const float4*)&Bp[k0 + BK + q * 4];
            }
        }
#pragma unroll
        for (int kk = 0; kk < BK; ++kk) {
            float4 a0 = *(const float4*)&As[kk * 64 + ty * 8];
            float4 a1 = *(const float4*)&As[kk * 64 + ty * 8 + 4];
            float4 b0 = *(const float4*)&Bs[kk * 64 + tx * 8];
            float4 b1 = *(const float4*)&Bs[kk * 64 + tx * 8 + 4];
            float ar[8] = {a0.x, a0.y, a0.z, a0.w, a1.x, a1.y, a1.z, a1.w};
            float br[8] = {b0.x, b0.y, b0.z, b0.w, b1.x, b1.y, b1.z, b1.w};
#pragma unroll
            for (int i = 0; i < 8; ++i)
#pragma unroll
                for (int j = 0; j < 8; ++j) acc[i][j] += ar[i] * br[j];
        }
    }

    // ---- reduce 4 wave-partials: R0 = w0 + w2, R1 = w1 + w3, result = R0 + R1
    float* R0 = smem;
    float* R1 = smem + BM * RP;
    __syncthreads();
    if (wave < 2) {
        float* R = (wave == 0) ? R0 : R1;
#pragma unroll
        for (int i = 0; i < 8; ++i) {
            int r = ty * 8 + i;
            *(float4*)&R[r * RP + tx * 8] =
                make_float4(acc[i][0], acc[i][1], acc[i][2], acc[i][3]);
            *(float4*)&R[r * RP + tx * 8 + 4] =
                make_float4(acc[i][4], acc[i][5], acc[i][6], acc[i][7]);
        }
    }
    __syncthreads();
    if (wave >= 2) {
        float* R = (wave == 2) ? R0 : R1;
#pragma unroll
        for (int i = 0; i < 8; ++i) {
            int r = ty * 8 + i;
            float4 p0 = *(const float4*)&R[r * RP + tx * 8];
            float4 p1 = *(const float4*)&R[r * RP + tx * 8 + 4];
            p0.x += acc[i][0]; p0.y += acc[i][1]; p0.z += acc[i][2]; p0.w += acc[i][3];
            p1.x += acc[i][4]; p1.y += acc[i][5]; p1.z += acc[i][6]; p1.w += acc[i][7];
            *(float4*)&R[r * RP + tx * 8]     = p0;
            *(float4*)&R[r * RP + tx * 8 + 4] = p1;
        }
    }
    __syncthreads();

    // ---- epilogue: wave w owns rows [w*16, w*16+16); 4 lanes per row, 16 cols per lane
    const int row = wave * 16 + (lane >> 2);
    const int c0 = (lane & 3) * 16;
    float v[16];
#pragma unroll
    for (int g = 0; g < 4; ++g) {
        float4 s0 = *(const float4*)&R0[row * RP + c0 + g * 4];
        float4 s1 = *(const float4*)&R1[row * RP + c0 + g * 4];
        v[g*4+0] = s0.x + s1.x; v[g*4+1] = s0.y + s1.y;
        v[g*4+2] = s0.z + s1.z; v[g*4+3] = s0.w + s1.w;
    }
    if (is_logits) {
        const int r = m0 + row;
        unsigned long long best = 0ULL;
#pragma unroll
        for (int g = 0; g < 4; ++g) {
            float4 gg = *(const float4*)&gum_t[(size_t)r * VOCAB + n0 + c0 + g * 4];
            float4 ob = *(const float4*)&outb[n0 + c0 + g * 4];
            float gv[4] = {gg.x, gg.y, gg.z, gg.w};
            float obv[4] = {ob.x, ob.y, ob.z, ob.w};
#pragma unroll
            for (int e = 0; e < 4; ++e) {
                unsigned long long key =
                    pack_key(v[g*4+e] + obv[e] + gv[e], n0 + c0 + g * 4 + e);
                if (key > best) best = key;
            }
        }
#pragma unroll
        for (int s = 1; s < 4; s <<= 1) {
            unsigned long long o = __shfl_xor(best, s);
            if (o > best) best = o;
        }
        if ((lane & 3) == 0) atomicMax(&keys_t[r], best);
    } else {
        float* Go = Gp + (size_t)(m0 + row) * GIH + n0 + c0;
#pragma unroll
        for (int g = 0; g < 4; ++g)
            *(float4*)&Go[g * 4] = make_float4(v[g*4+0], v[g*4+1], v[g*4+2], v[g*4+3]);
    }
}

// ---------------- GRU elementwise: h = (1-z)*n + z*h  (single full-K Gp; bih folded in P)
__global__ __launch_bounds__(256) void k_gru(const float* __restrict__ Gp,
                                             const float* __restrict__ P,
                                             const float* __restrict__ bhh,
                                             const unsigned long long* __restrict__ keys_prev,
                                             float* __restrict__ h) {
    int idx = blockIdx.x * 256 + threadIdx.x;    // 0..65535
    int b = idx >> 7;
    int j4 = (idx & 127) << 2;
    int tok = SOS;
    if (keys_prev) tok = (VOCAB - 1) - (int)(uint32_t)(keys_prev[b] & 0xffffffffULL);
    const float* Pr = P + (size_t)tok * GIH;
    const float* G0 = Gp + (size_t)b * GIH;
    float4 ir = *(const float4*)&Pr[j4];
    float4 iz = *(const float4*)&Pr[j4 + HIDDEN];
    float4 in_ = *(const float4*)&Pr[j4 + 2 * HIDDEN];
    float4 hr0 = *(const float4*)&G0[j4];
    float4 hz0 = *(const float4*)&G0[j4 + HIDDEN];
    float4 hn0 = *(const float4*)&G0[j4 + 2 * HIDDEN];
    float4 bhr = *(const float4*)&bhh[j4];
    float4 bhz = *(const float4*)&bhh[j4 + HIDDEN];
    float4 bhn = *(const float4*)&bhh[j4 + 2 * HIDDEN];
    float4 ho = *(const float4*)&h[(size_t)b * HIDDEN + j4];
    float irr[4] = {ir.x, ir.y, ir.z, ir.w};
    float izz[4] = {iz.x, iz.y, iz.z, iz.w};
    float inn[4] = {in_.x, in_.y, in_.z, in_.w};
    float hrr[4] = {hr0.x + bhr.x, hr0.y + bhr.y, hr0.z + bhr.z, hr0.w + bhr.w};
    float hzz[4] = {hz0.x + bhz.x, hz0.y + bhz.y, hz0.z + bhz.z, hz0.w + bhz.w};
    float hnn[4] = {hn0.x + bhn.x, hn0.y + bhn.y, hn0.z + bhn.z, hn0.w + bhn.w};
    float hov[4] = {ho.x, ho.y, ho.z, ho.w};
    float res[4];
#pragma unroll
    for (int i = 0; i < 4; ++i) {
        float r = 1.0f / (1.0f + expf(-(irr[i] + hrr[i])));
        float z = 1.0f / (1.0f + expf(-(izz[i] + hzz[i])));
        float n = tanhf(inn[i] + r * hnn[i]);
        res[i] = (1.0f - z) * n + z * hov[i];
    }
    *(float4*)&h[(size_t)b * HIDDEN + j4] = make_float4(res[0], res[1], res[2], res[3]);
}

// ---------------- finalize
__global__ __launch_bounds__(256) void k_final(const unsigned long long* __restrict__ keys,
                                               float* __restrict__ out) {
    int b = blockIdx.x * 256 + threadIdx.x;
    if (b >= BATCH) return;
    int toks[TSTEPS];
    int len = 1;
    bool done = false;
#pragma unroll
    for (int t = 0; t < TSTEPS; ++t) {
        int tok = (VOCAB - 1) - (int)(uint32_t)(keys[(size_t)t * BATCH + b] & 0xffffffffULL);
        toks[t] = tok;
        if (!done) len++;
        if (tok == EOS) done = true;
    }
    if (!done) len++;
    float* lang = out + (size_t)b * MAXLEN * VOCAB;
    lang[SOS] = 1.0f;
#pragma unroll
    for (int t = 0; t < TSTEPS; ++t) {
        int pos = t + 1;
        if (pos < len) lang[(size_t)pos * VOCAB + toks[t]] = 1.0f;
    }
    if (len == MAXLEN) lang[(size_t)(MAXLEN - 1) * VOCAB + EOS] = 1.0f;
    out[(size_t)BATCH * MAXLEN * VOCAB + b] = (float)len;
    if (b == 0) out[(size_t)BATCH * MAXLEN * VOCAB + BATCH] = 0.0f;
}

extern "C" void kernel_launch(void* const* d_in, const int* in_sizes, int n_in,
                              void* d_out, int out_size, void* d_ws, size_t ws_size,
                              hipStream_t stream) {
    const float* feats = (const float*)d_in[0];
    const int*   targets = (const int*)d_in[1];
    const float* featW = (const float*)d_in[2];
    const float* featb = (const float*)d_in[3];
    const float* embW  = (const float*)d_in[4];
    const float* initW = (const float*)d_in[5];
    const float* initb = (const float*)d_in[6];
    const float* Wih   = (const float*)d_in[7];
    const float* Whh   = (const float*)d_in[8];
    const float* bih   = (const float*)d_in[9];
    const float* bhh   = (const float*)d_in[10];
    const float* outW  = (const float*)d_in[11];
    const float* outb  = (const float*)d_in[12];
    const float* gumbel = (const float*)d_in[13];
    float* out = (float*)d_out;

    // workspace layout:
    char* ws = (char*)d_ws;
    float* h  = (float*)(ws);                                    // 1 MB
    unsigned long long* keys = (unsigned long long*)(ws + (1 << 20));  // 152 KB
    float* Gp = (float*)(ws + 5 * (1 << 18));                    // @1.25 MB: 512x1536x4 = 3 MB
    float* fe = Gp;                                              // alias: fe (3 MB) dead before Gp use
    float* P  = (float*)(ws + 8 * (1 << 20));                    // @8 MB: 25.17 MB

    int zb = (out_size + 4095) / 4096;
    k_zero<<<dim3(zb), 256, 0, stream>>>(out, out_size, keys);

    k_fe<<<dim3(FEATSZ / BM, (BATCH * NOBJ) / BM), 256, 0, stream>>>(feats, featW, featb, fe);
    k_h0<<<dim3(HIDDEN / BM, BATCH / BM), 256, 0, stream>>>(fe, initW, initb, targets, h);
    k_P<<<dim3(GIH / 128, VOCAB / BM), 256, 0, stream>>>(embW, Wih, bih, P);

    // prime gatesH(0) from h0 — gates blocks only (bx_off=512)
    k_step<<<dim3(NGATES_BLK), 256, 0, stream>>>(h, Whh, Gp, outW, outb, gumbel, keys,
                                                 NLOGITS_BLK);

    for (int t = 0; t < TSTEPS; ++t) {
        const unsigned long long* kprev = (t == 0) ? nullptr : (keys + (size_t)(t - 1) * BATCH);
        k_gru<<<dim3(BATCH * HIDDEN / 4 / 256), 256, 0, stream>>>(Gp, P, bhh, kprev, h);
        int nblk = (t < TSTEPS - 1) ? NSTEP_BLK : NLOGITS_BLK;   // last step: logits only
        k_step<<<dim3(nblk), 256, 0, stream>>>(
            h, Whh, Gp, outW, outb, gumbel + (size_t)t * BATCH * VOCAB,
            keys + (size_t)t * BATCH, 0);
    }
    k_final<<<dim3(2), 256, 0, stream>>>(keys, out);
}